// Round 5
// baseline (201.656 us; speedup 1.0000x reference)
//
#include <hip/hip_runtime.h>
#include <hip/hip_bf16.h>
#include <math.h>

#define FLT_MAX_F 3.4028234663852886e38f
#define PITCH 132   // 128 + 4 floats: 16B-aligned rows, consecutive m -> consecutive banks

typedef __attribute__((ext_vector_type(8))) short short8;   // 8 bf16 = 4 VGPRs (MFMA A/B frag)
typedef __attribute__((ext_vector_type(4))) float f32x4;    // MFMA C/D frag

// ---------------- bf16 split helpers ----------------
// a = hi + lo with hi = bf16_rne(a), lo = bf16_rne(a - hi). 3-term MFMA product
// hi*hi + lo*hi + hi*lo has relative error ~2^-18 (drops only lo*lo).
__device__ __forceinline__ void split8(const float4 a0, const float4 a1,
                                       short8& hi, short8& lo) {
    float a[8] = {a0.x, a0.y, a0.z, a0.w, a1.x, a1.y, a1.z, a1.w};
#pragma unroll
    for (int p = 0; p < 4; ++p) {
        float2 f = make_float2(a[2 * p], a[2 * p + 1]);
        __hip_bfloat162 h = __float22bfloat162_rn(f);          // v_cvt_pk_bf16_f32
        float2 hf = __bfloat1622float2(h);
        __hip_bfloat162 l = __float22bfloat162_rn(make_float2(f.x - hf.x, f.y - hf.y));
        union { __hip_bfloat162 b; short2 s; } uh, ul;
        uh.b = h; ul.b = l;
        hi[2 * p] = uh.s.x; hi[2 * p + 1] = uh.s.y;
        lo[2 * p] = ul.s.x; lo[2 * p + 1] = ul.s.y;
    }
}

// ---------------- weight prep: fp32 W -> bf16 hi/lo in B-fragment order ----------------
// Vectorized: one thread = one (chunk, lane) unit -> 8 strided W reads (coalesced across
// lanes: 16 consecutive n per quad) + two contiguous 16B stores (perfectly coalesced).
// Fragment layout for mfma_f32_16x16x32_bf16:
//   B: lane l holds B[k = s*32 + (l>>4)*8 + j][n = ct*16 + (l&15)]
// ws layout (shorts): chunk cp = s*NT + ct occupies 1024 shorts:
//   [cp*1024 + lane*8 + j] = hi, [cp*1024 + 512 + lane*8 + j] = lo.
// Layer bases (shorts): L0=0 (64x128), L1=16384 (128x128), L2=49152 (128x64), L3=65536 (64x32).
__global__ void prep_weights(const float* __restrict__ W0, const float* __restrict__ W1,
                             const float* __restrict__ W2, const float* __restrict__ W3,
                             short* __restrict__ ws) {
    int e = blockIdx.x * 256 + threadIdx.x;     // unit id, 4352 total
    const float* W; int N, NT, base, ul;
    if (e < 1024)      { W = W0; N = 128; NT = 8; base = 0;     ul = e; }
    else if (e < 3072) { W = W1; N = 128; NT = 8; base = 16384; ul = e - 1024; }
    else if (e < 4096) { W = W2; N = 64;  NT = 4; base = 49152; ul = e - 3072; }
    else if (e < 4352) { W = W3; N = 32;  NT = 2; base = 65536; ul = e - 4096; }
    else return;
    const int cp = ul >> 6, lane = ul & 63;
    const int s = cp / NT, ct = cp % NT;
    const int k0 = s * 32 + (lane >> 4) * 8;
    const int n = ct * 16 + (lane & 15);
    short8 hv, lv;
#pragma unroll
    for (int j = 0; j < 8; ++j) {
        float w = W[(size_t)(k0 + j) * N + n];
        __hip_bfloat16 h = __float2bfloat16(w);
        float hf = __bfloat162float(h);
        __hip_bfloat16 l = __float2bfloat16(w - hf);
        union { __hip_bfloat16 b; short s; } ph, pl;
        ph.b = h; pl.b = l;
        hv[j] = ph.s; lv[j] = pl.s;
    }
    *(short8*)(ws + base + cp * 1024 + lane * 8) = hv;
    *(short8*)(ws + base + cp * 1024 + 512 + lane * 8) = lv;
}

// ---------------- per-wave layer compute: 2 m-tiles share every B fragment ----------------
template <int K, int N>
__device__ __forceinline__ void layer_frag2(const short8* __restrict__ wf,
                                            const float* __restrict__ bias,
                                            const short8 (&ah)[2][4], const short8 (&al)[2][4],
                                            int lane, int m, f32x4 (&acc)[2][8]) {
    constexpr int NK = K / 32, NT = N / 16;
#pragma unroll
    for (int ct = 0; ct < NT; ++ct) {
        float b = bias[ct * 16 + m];
        acc[0][ct] = f32x4{b, b, b, b};
        acc[1][ct] = f32x4{b, b, b, b};
    }
#pragma unroll
    for (int s = 0; s < NK; ++s) {
#pragma unroll
        for (int ct = 0; ct < NT; ++ct) {
            const short8* ch = wf + (size_t)(s * NT + ct) * 128;
            short8 bh = ch[lane];
            short8 bl = ch[64 + lane];
            // 6 MFMAs per B-load (2 independent acc chains interleaved for ILP)
            acc[0][ct] = __builtin_amdgcn_mfma_f32_16x16x32_bf16(ah[0][s], bh, acc[0][ct], 0, 0, 0);
            acc[1][ct] = __builtin_amdgcn_mfma_f32_16x16x32_bf16(ah[1][s], bh, acc[1][ct], 0, 0, 0);
            acc[0][ct] = __builtin_amdgcn_mfma_f32_16x16x32_bf16(al[0][s], bh, acc[0][ct], 0, 0, 0);
            acc[1][ct] = __builtin_amdgcn_mfma_f32_16x16x32_bf16(al[1][s], bh, acc[1][ct], 0, 0, 0);
            acc[0][ct] = __builtin_amdgcn_mfma_f32_16x16x32_bf16(ah[0][s], bl, acc[0][ct], 0, 0, 0);
            acc[1][ct] = __builtin_amdgcn_mfma_f32_16x16x32_bf16(al[1][s], bl, acc[1][ct], 0, 0, 0) ;
        }
    }
}

template <int K>
__device__ __forceinline__ void load_a_lds(const float* __restrict__ lw, int m, int q,
                                           short8 ah[4], short8 al[4]) {
    const float* rp = lw + m * PITCH + q * 8;
    float4 v[K / 16];
#pragma unroll
    for (int s = 0; s < K / 32; ++s) {       // all ds_read_b128 in flight first
        v[2 * s]     = *(const float4*)(rp + s * 32);
        v[2 * s + 1] = *(const float4*)(rp + s * 32 + 4);
    }
#pragma unroll
    for (int s = 0; s < K / 32; ++s) split8(v[2 * s], v[2 * s + 1], ah[s], al[s]);
}

template <int N>
__device__ __forceinline__ void store_d_lds(float* __restrict__ lw, int m, int q,
                                            const f32x4* acc, bool relu) {
#pragma unroll
    for (int ct = 0; ct < N / 16; ++ct) {
#pragma unroll
        for (int r = 0; r < 4; ++r) {
            float v = acc[ct][r];
            if (relu) v = fmaxf(v, 0.0f);
            lw[(q * 4 + r) * PITCH + ct * 16 + m] = v;
        }
    }
}

// ---------------- fast E1: Abramowitz-Stegun rational approximations ----------------
// li(1-u) = Ei(t) = -E1(-t), t = log(1-u) < 0; x = -t in (1e-4, 9.3).
// x < 1:  5.1.53 polynomial + log, |err| < 2e-7;  x >= 1: 5.1.54 rational, |err| < 2e-8.
__device__ __forceinline__ float expi_neg_fast(float t) {
    float x = -t;
    float e1s = -__logf(x) + (-0.57721566f + x * (0.99999193f + x * (-0.24991055f
              + x * (0.05519968f + x * (-0.00976004f + x * 0.00107857f)))));
    float num = 0.2677737343f + x * (8.6347608925f + x * (18.0590169730f
              + x * (8.5733287401f + x)));
    float den = 3.9584969228f + x * (21.0996530827f + x * (25.6329561486f
              + x * (9.5733223454f + x)));
    float e1l = __expf(-x) * num * __builtin_amdgcn_rcpf(x * den);
    float e1 = (x < 1.0f) ? e1s : e1l;
    return -e1;
}

__global__ __launch_bounds__(128, 2) void mlp_phi_mfma(
    const float* __restrict__ u,
    const float* __restrict__ b0, const float* __restrict__ b1,
    const float* __restrict__ b2, const float* __restrict__ b3,
    const short* __restrict__ ws,
    const float* __restrict__ var1, const float* __restrict__ var2,
    const float* __restrict__ var3, const float* __restrict__ var4,
    const float* __restrict__ var5, const float* __restrict__ var6,
    float* __restrict__ out) {
    // 2 waves/block, each wave owns 32 rows (two 16-row m-tiles) end-to-end.
    // No __syncthreads anywhere. LDS 33792 B -> 4 blocks/CU.
    __shared__ float lds[2 * 32 * PITCH];
    const int t = threadIdx.x, lane = t & 63, wave = t >> 6;
    const int m = lane & 15, q = lane >> 4;
    float* lw = lds + wave * 32 * PITCH;               // 32-row tile for this wave
    const size_t row0 = (size_t)blockIdx.x * 64 + wave * 32;

    const short8* wf0 = (const short8*)(ws);
    const short8* wf1 = (const short8*)(ws + 16384);
    const short8* wf2 = (const short8*)(ws + 49152);
    const short8* wf3 = (const short8*)(ws + 65536);

    short8 ah[2][4], al[2][4];
    f32x4 acc[2][8];

    // ---- Layer 0 (64 -> 128): A straight from global u ----
#pragma unroll
    for (int mt = 0; mt < 2; ++mt) {
        const float* up = u + (row0 + mt * 16 + m) * 64;
        float4 v[4];
#pragma unroll
        for (int s = 0; s < 2; ++s) {
            v[2 * s]     = *(const float4*)(up + s * 32 + q * 8);
            v[2 * s + 1] = *(const float4*)(up + s * 32 + q * 8 + 4);
        }
#pragma unroll
        for (int s = 0; s < 2; ++s) split8(v[2 * s], v[2 * s + 1], ah[mt][s], al[mt][s]);
    }
    layer_frag2<64, 128>(wf0, b0, ah, al, lane, m, acc);
#pragma unroll
    for (int mt = 0; mt < 2; ++mt) store_d_lds<128>(lw + mt * 16 * PITCH, m, q, acc[mt], true);

    // ---- Layer 1 (128 -> 128) ----
#pragma unroll
    for (int mt = 0; mt < 2; ++mt) load_a_lds<128>(lw + mt * 16 * PITCH, m, q, ah[mt], al[mt]);
    layer_frag2<128, 128>(wf1, b1, ah, al, lane, m, acc);
#pragma unroll
    for (int mt = 0; mt < 2; ++mt) store_d_lds<128>(lw + mt * 16 * PITCH, m, q, acc[mt], true);

    // ---- Layer 2 (128 -> 64) ----
#pragma unroll
    for (int mt = 0; mt < 2; ++mt) load_a_lds<128>(lw + mt * 16 * PITCH, m, q, ah[mt], al[mt]);
    layer_frag2<128, 64>(wf2, b2, ah, al, lane, m, acc);
#pragma unroll
    for (int mt = 0; mt < 2; ++mt) store_d_lds<64>(lw + mt * 16 * PITCH, m, q, acc[mt], true);

    // ---- Layer 3 (64 -> 32): net stays in registers ----
#pragma unroll
    for (int mt = 0; mt < 2; ++mt) load_a_lds<64>(lw + mt * 16 * PITCH, m, q, ah[mt], al[mt]);

    // Prefetch epilogue u values so their latency hides behind layer-3 MFMAs.
    float ue[2][8];
#pragma unroll
    for (int mt = 0; mt < 2; ++mt)
#pragma unroll
        for (int ot = 0; ot < 2; ++ot)
#pragma unroll
            for (int r = 0; r < 4; ++r)
                ue[mt][ot * 4 + r] = u[(row0 + mt * 16 + q * 4 + r) * 64 + ot * 16 + m];

    layer_frag2<64, 32>(wf3, b3, ah, al, lane, m, acc);   // acc[mt][0..1] = net tiles

    // ---- Epilogue: lane holds net[row=mt*16+q*4+r][col=ot*16+m] ----
#pragma unroll
    for (int mt = 0; mt < 2; ++mt) {
#pragma unroll
        for (int ot = 0; ot < 2; ++ot) {
            const int d = ot * 16 + m;
            const float v1 = var1[d], v2 = var2[d], v3 = var3[d],
                        v4 = var4[d], v5 = var5[d], v6 = var6[d];
#pragma unroll
            for (int r = 0; r < 4; ++r) {
                const size_t row = row0 + mt * 16 + q * 4 + r;
                const float net = acc[mt][ot][r];
                const float ud = ue[mt][ot * 4 + r];

                const float lt = __logf(1.0f - ud);      // log_term < 0
                const float li = expi_neg_fast(lt);
                const float omu = 1.0f - ud;

                const float rl = __builtin_amdgcn_rcpf(lt);   // 1/log_term
                const float phi = v2 * rl
                                + v3 * li
                                + v4 * (omu * rl - li)
                                + v5 * (omu * (lt + 1.0f) * 0.5f * (rl * rl) - 0.5f * li);

                const float ud2 = ud * ud;
                const float ud4 = ud2 * ud2;
                const float p01 = -4.0f * ud4 * ud + 5.0f * ud4;

                float corr1 = p01 * (v1 + phi);
                if (isnan(corr1)) {
                    corr1 = 0.0f;
                } else if (isinf(corr1)) {
                    corr1 = copysignf(FLT_MAX_F, corr1);
                }
                const float corr2 = v6 * (ud * ud2 - 2.0f * ud2 + ud);

                float nt = net + corr1 + corr2;
                nt = fmaxf(nt, 0.0f);

                const float base = (1.0f - ud2) * 0.5f;
                out[row * 32 + d] = __expf(-nt * __logf(base));
            }
        }
    }
}

extern "C" void kernel_launch(void* const* d_in, const int* in_sizes, int n_in,
                              void* d_out, int out_size, void* d_ws, size_t ws_size,
                              hipStream_t stream) {
    const float* u    = (const float*)d_in[0];
    const float* W0   = (const float*)d_in[1];
    const float* b0   = (const float*)d_in[2];
    const float* W1   = (const float*)d_in[3];
    const float* b1   = (const float*)d_in[4];
    const float* W2   = (const float*)d_in[5];
    const float* b2   = (const float*)d_in[6];
    const float* W3   = (const float*)d_in[7];
    const float* b3   = (const float*)d_in[8];
    const float* var1 = (const float*)d_in[9];
    const float* var2 = (const float*)d_in[10];
    const float* var3 = (const float*)d_in[11];
    const float* var4 = (const float*)d_in[12];
    const float* var5 = (const float*)d_in[13];
    const float* var6 = (const float*)d_in[14];
    float* out = (float*)d_out;
    short* ws = (short*)d_ws;   // needs 139,264 B

    // Convert weights to bf16 hi/lo fragment layout (same work every launch).
    prep_weights<<<dim3(17), dim3(256), 0, stream>>>(W0, W1, W2, W3, ws);

    const int B = in_sizes[0] / 64;        // 262144 rows
    const int blocks = B / 64;             // 64 rows per block (32 per wave)
    mlp_phi_mfma<<<dim3(blocks), dim3(128), 0, stream>>>(
        u, b0, b1, b2, b3, ws,
        var1, var2, var3, var4, var5, var6, out);
}

// Round 6
// 168.791 us; speedup vs baseline: 1.1947x; 1.1947x over previous
//
#include <hip/hip_runtime.h>
#include <hip/hip_bf16.h>
#include <math.h>

#define FLT_MAX_F 3.4028234663852886e38f
#define PITCH_H 136   // halfs: 128 + 8 pad; rows stay 16B-aligned, bank stride non-pow2

typedef _Float16 half8 __attribute__((ext_vector_type(8)));  // 8 f16 = 4 VGPRs (MFMA A/B frag)
typedef __attribute__((ext_vector_type(4))) float f32x4;     // MFMA C/D frag
typedef __attribute__((ext_vector_type(8))) short short8;

// ---------------- weight prep: fp32 W -> f16 in B-fragment order ----------------
// One thread = one (chunk, lane) unit: 8 strided W reads (lanes cover 16 consecutive n
// -> 64B segments), one contiguous 16B store.
// Fragment layout for mfma_f32_16x16x32_f16 (same mapping family as bf16, m89-verified):
//   B: lane l holds B[k = s*32 + (l>>4)*8 + j][n = ct*16 + (l&15)], j=0..7
// ws layout (shorts): chunk cp = s*NT + ct occupies 512 shorts at [cp*512 + lane*8 + j].
// Layer bases (shorts): L0=0 (64x128,CP16), L1=8192 (128x128,CP32), L2=24576 (128x64,CP16),
// L3=32768 (64x32,CP4). Total 34816 shorts = 69632 B.
__global__ void prep_weights(const float* __restrict__ W0, const float* __restrict__ W1,
                             const float* __restrict__ W2, const float* __restrict__ W3,
                             short* __restrict__ ws) {
    int e = blockIdx.x * 256 + threadIdx.x;     // unit id, 4352 total
    const float* W; int N, NT, base, ul;
    if (e < 1024)      { W = W0; N = 128; NT = 8; base = 0;     ul = e; }
    else if (e < 3072) { W = W1; N = 128; NT = 8; base = 8192;  ul = e - 1024; }
    else if (e < 4096) { W = W2; N = 64;  NT = 4; base = 24576; ul = e - 3072; }
    else if (e < 4352) { W = W3; N = 32;  NT = 2; base = 32768; ul = e - 4096; }
    else return;
    const int cp = ul >> 6, lane = ul & 63;
    const int s = cp / NT, ct = cp % NT;
    const int k0 = s * 32 + (lane >> 4) * 8;
    const int n = ct * 16 + (lane & 15);
    union { half8 h; short8 s; } v;
#pragma unroll
    for (int j = 0; j < 8; ++j) v.h[j] = (_Float16)W[(size_t)(k0 + j) * N + n];
    *(short8*)(ws + base + cp * 512 + lane * 8) = v.s;
}

// ---------------- per-wave layer compute: group-of-G register double-buffer ----------------
// B-fragment loads for group g+1 issue before group g's MFMAs -> ~8 loads in flight,
// covering L2 latency (~200 cyc) with 4 waves/SIMD.
template <int K, int N, int G>
__device__ __forceinline__ void layer_frag(const half8* __restrict__ wf,
                                           const float* __restrict__ bias,
                                           const half8 af[K / 32], int lane, int m,
                                           f32x4* acc) {
    constexpr int NK = K / 32, NT = N / 16, CP = NK * NT, NG = CP / G;
    static_assert(CP % G == 0, "group must divide chunk count");
    half8 buf[2][G];
#pragma unroll
    for (int i = 0; i < G; ++i) buf[0][i] = wf[i * 64 + lane];
#pragma unroll
    for (int ct = 0; ct < NT; ++ct) {
        float b = bias[ct * 16 + m];
        acc[ct] = f32x4{b, b, b, b};
    }
#pragma unroll
    for (int g = 0; g < NG; ++g) {
        constexpr int dummy = 0; (void)dummy;
        const int cur = g & 1, nxt = cur ^ 1;
        if (g + 1 < NG) {
#pragma unroll
            for (int i = 0; i < G; ++i)
                buf[nxt][i] = wf[(size_t)((g + 1) * G + i) * 64 + lane];
        }
#pragma unroll
        for (int i = 0; i < G; ++i) {
            const int cp = g * G + i, s = cp / NT, ct = cp % NT;  // s-major: acc[ct] rotates
            acc[ct] = __builtin_amdgcn_mfma_f32_16x16x32_f16(af[s], buf[cur][i], acc[ct], 0, 0, 0);
        }
    }
}

// A-fragments read straight from the f16 LDS tile: one ds_read_b128 per chunk, zero VALU.
template <int K>
__device__ __forceinline__ void load_a_lds(const _Float16* __restrict__ lw, int m, int q,
                                           half8 af[K / 32]) {
    const _Float16* rp = lw + m * PITCH_H + q * 8;
#pragma unroll
    for (int s = 0; s < K / 32; ++s) af[s] = *(const half8*)(rp + s * 32);
}

template <int N>
__device__ __forceinline__ void store_d_lds(_Float16* __restrict__ lw, int m, int q,
                                            const f32x4* acc, bool relu) {
#pragma unroll
    for (int ct = 0; ct < N / 16; ++ct) {
#pragma unroll
        for (int r = 0; r < 4; ++r) {
            float v = acc[ct][r];
            if (relu) v = fmaxf(v, 0.0f);
            lw[(q * 4 + r) * PITCH_H + ct * 16 + m] = (_Float16)v;   // ds_write_b16
        }
    }
}

// ---------------- fast E1: Abramowitz-Stegun rational approximations ----------------
// li(1-u) = Ei(t) = -E1(-t), t = log(1-u) < 0; x = -t in (1e-4, 9.3).
// x < 1:  5.1.53 polynomial + log, |err| < 2e-7;  x >= 1: 5.1.54 rational, |err| < 2e-8.
__device__ __forceinline__ float expi_neg_fast(float t) {
    float x = -t;
    float e1s = -__logf(x) + (-0.57721566f + x * (0.99999193f + x * (-0.24991055f
              + x * (0.05519968f + x * (-0.00976004f + x * 0.00107857f)))));
    float num = 0.2677737343f + x * (8.6347608925f + x * (18.0590169730f
              + x * (8.5733287401f + x)));
    float den = 3.9584969228f + x * (21.0996530827f + x * (25.6329561486f
              + x * (9.5733223454f + x)));
    float e1l = __expf(-x) * num * __builtin_amdgcn_rcpf(x * den);
    float e1 = (x < 1.0f) ? e1s : e1l;
    return -e1;
}

__global__ __launch_bounds__(256, 4) void mlp_phi_mfma(
    const float* __restrict__ u,
    const float* __restrict__ b0, const float* __restrict__ b1,
    const float* __restrict__ b2, const float* __restrict__ b3,
    const short* __restrict__ ws,
    const float* __restrict__ var1, const float* __restrict__ var2,
    const float* __restrict__ var3, const float* __restrict__ var4,
    const float* __restrict__ var5, const float* __restrict__ var6,
    float* __restrict__ out) {
    // 4 waves/block, each wave owns 16 rows end-to-end. No __syncthreads anywhere.
    // f16 activation tiles: 4 x 16 x 136 x 2B = 17408 B LDS.
    __shared__ __align__(16) _Float16 lds[4 * 16 * PITCH_H];
    const int t = threadIdx.x, lane = t & 63, wave = t >> 6;
    const int m = lane & 15, q = lane >> 4;
    _Float16* lw = lds + wave * 16 * PITCH_H;
    const size_t row0 = (size_t)blockIdx.x * 64 + wave * 16;

    const half8* wf0 = (const half8*)(ws);
    const half8* wf1 = (const half8*)(ws + 8192);
    const half8* wf2 = (const half8*)(ws + 24576);
    const half8* wf3 = (const half8*)(ws + 32768);

    half8 af[4];
    f32x4 acc[8];

    // ---- Layer 0 (64 -> 128): A straight from global u, cvt fp32->f16 ----
    {
        const float* up = u + (row0 + m) * 64;
#pragma unroll
        for (int s = 0; s < 2; ++s) {
            float4 v0 = *(const float4*)(up + s * 32 + q * 8);
            float4 v1 = *(const float4*)(up + s * 32 + q * 8 + 4);
            half8 a;
            a[0] = (_Float16)v0.x; a[1] = (_Float16)v0.y;
            a[2] = (_Float16)v0.z; a[3] = (_Float16)v0.w;
            a[4] = (_Float16)v1.x; a[5] = (_Float16)v1.y;
            a[6] = (_Float16)v1.z; a[7] = (_Float16)v1.w;
            af[s] = a;
        }
    }
    layer_frag<64, 128, 8>(wf0, b0, af, lane, m, acc);
    store_d_lds<128>(lw, m, q, acc, true);

    // ---- Layer 1 (128 -> 128) ----
    load_a_lds<128>(lw, m, q, af);
    layer_frag<128, 128, 8>(wf1, b1, af, lane, m, acc);
    store_d_lds<128>(lw, m, q, acc, true);

    // ---- Layer 2 (128 -> 64) ----
    load_a_lds<128>(lw, m, q, af);
    layer_frag<128, 64, 8>(wf2, b2, af, lane, m, acc);
    store_d_lds<64>(lw, m, q, acc, true);

    // ---- Layer 3 (64 -> 32): net stays in registers ----
    load_a_lds<64>(lw, m, q, af);

    // Prefetch epilogue u values so their latency hides behind layer-3 MFMAs.
    float ue[8];
#pragma unroll
    for (int ot = 0; ot < 2; ++ot)
#pragma unroll
        for (int r = 0; r < 4; ++r)
            ue[ot * 4 + r] = u[(row0 + q * 4 + r) * 64 + ot * 16 + m];

    layer_frag<64, 32, 4>(wf3, b3, af, lane, m, acc);   // acc[0..1] = net tiles

    // ---- Epilogue: lane holds net[row=q*4+r][col=ot*16+m], fp32 throughout ----
#pragma unroll
    for (int ot = 0; ot < 2; ++ot) {
        const int d = ot * 16 + m;
        const float v1 = var1[d], v2 = var2[d], v3 = var3[d],
                    v4 = var4[d], v5 = var5[d], v6 = var6[d];
#pragma unroll
        for (int r = 0; r < 4; ++r) {
            const size_t row = row0 + q * 4 + r;
            const float net = acc[ot][r];
            const float ud = ue[ot * 4 + r];

            const float lt = __logf(1.0f - ud);      // log_term < 0
            const float li = expi_neg_fast(lt);
            const float omu = 1.0f - ud;

            const float rl = __builtin_amdgcn_rcpf(lt);   // 1/log_term
            const float phi = v2 * rl
                            + v3 * li
                            + v4 * (omu * rl - li)
                            + v5 * (omu * (lt + 1.0f) * 0.5f * (rl * rl) - 0.5f * li);

            const float ud2 = ud * ud;
            const float ud4 = ud2 * ud2;
            const float p01 = -4.0f * ud4 * ud + 5.0f * ud4;

            float corr1 = p01 * (v1 + phi);
            if (isnan(corr1)) {
                corr1 = 0.0f;
            } else if (isinf(corr1)) {
                corr1 = copysignf(FLT_MAX_F, corr1);
            }
            const float corr2 = v6 * (ud * ud2 - 2.0f * ud2 + ud);

            float nt = net + corr1 + corr2;
            nt = fmaxf(nt, 0.0f);

            const float base = (1.0f - ud2) * 0.5f;
            out[row * 32 + d] = __expf(-nt * __logf(base));
        }
    }
}

extern "C" void kernel_launch(void* const* d_in, const int* in_sizes, int n_in,
                              void* d_out, int out_size, void* d_ws, size_t ws_size,
                              hipStream_t stream) {
    const float* u    = (const float*)d_in[0];
    const float* W0   = (const float*)d_in[1];
    const float* b0   = (const float*)d_in[2];
    const float* W1   = (const float*)d_in[3];
    const float* b1   = (const float*)d_in[4];
    const float* W2   = (const float*)d_in[5];
    const float* b2   = (const float*)d_in[6];
    const float* W3   = (const float*)d_in[7];
    const float* b3   = (const float*)d_in[8];
    const float* var1 = (const float*)d_in[9];
    const float* var2 = (const float*)d_in[10];
    const float* var3 = (const float*)d_in[11];
    const float* var4 = (const float*)d_in[12];
    const float* var5 = (const float*)d_in[13];
    const float* var6 = (const float*)d_in[14];
    float* out = (float*)d_out;
    short* ws = (short*)d_ws;   // needs 69,632 B

    // Convert weights to f16 fragment layout (same work every launch).
    prep_weights<<<dim3(17), dim3(256), 0, stream>>>(W0, W1, W2, W3, ws);

    const int B = in_sizes[0] / 64;        // 262144 rows
    const int blocks = B / 64;             // 64 rows per block (16 per wave)
    mlp_phi_mfma<<<dim3(blocks), dim3(256), 0, stream>>>(
        u, b0, b1, b2, b3, ws,
        var1, var2, var3, var4, var5, var6, out);
}

// Round 8
// 159.991 us; speedup vs baseline: 1.2604x; 1.0550x over previous
//
#include <hip/hip_runtime.h>
#include <hip/hip_bf16.h>
#include <math.h>

#define PITCH_H 136   // halfs: 128 + 8 pad; rows stay 16B-aligned, bank stride non-pow2
#define LN2_F 0.69314718055994531f

typedef _Float16 half8 __attribute__((ext_vector_type(8)));  // 8 f16 = 4 VGPRs (MFMA A/B frag)
typedef __attribute__((ext_vector_type(4))) float f32x4;     // MFMA C/D frag
typedef __attribute__((ext_vector_type(8))) short short8;

// ---------------- weight prep: fp32 W -> f16 in B-fragment order ----------------
// One thread = one (chunk, lane) unit: 8 strided W reads (lanes cover 16 consecutive n
// -> 64B segments), one contiguous 16B store.
// Fragment layout for mfma_f32_16x16x32_f16:
//   B: lane l holds B[k = s*32 + (l>>4)*8 + j][n = ct*16 + (l&15)], j=0..7
// ws layout (shorts): chunk cp = s*NT + ct occupies 512 shorts at [cp*512 + lane*8 + j].
// Layer bases (shorts): L0=0 (64x128,CP16), L1=8192 (128x128,CP32), L2=24576 (128x64,CP16),
// L3=32768 (64x32,CP4). Total 34816 shorts = 69632 B.
__global__ void prep_weights(const float* __restrict__ W0, const float* __restrict__ W1,
                             const float* __restrict__ W2, const float* __restrict__ W3,
                             short* __restrict__ ws) {
    int e = blockIdx.x * 256 + threadIdx.x;     // unit id, 4352 total
    const float* W; int N, NT, base, ul;
    if (e < 1024)      { W = W0; N = 128; NT = 8; base = 0;     ul = e; }
    else if (e < 3072) { W = W1; N = 128; NT = 8; base = 8192;  ul = e - 1024; }
    else if (e < 4096) { W = W2; N = 64;  NT = 4; base = 24576; ul = e - 3072; }
    else if (e < 4352) { W = W3; N = 32;  NT = 2; base = 32768; ul = e - 4096; }
    else return;
    const int cp = ul >> 6, lane = ul & 63;
    const int s = cp / NT, ct = cp % NT;
    const int k0 = s * 32 + (lane >> 4) * 8;
    const int n = ct * 16 + (lane & 15);
    union { half8 h; short8 s; } v;
#pragma unroll
    for (int j = 0; j < 8; ++j) v.h[j] = (_Float16)W[(size_t)(k0 + j) * N + n];
    *(short8*)(ws + base + cp * 512 + lane * 8) = v.s;
}

// ---------------- per-wave layer compute: 2 m-tiles share every B fragment ----------------
template <int K, int N>
__device__ __forceinline__ void layer_frag2(const half8* __restrict__ wf,
                                            const float* __restrict__ bias,
                                            const half8 (&af)[2][4], int lane, int m,
                                            f32x4 (&acc)[2][8]) {
    constexpr int NK = K / 32, NT = N / 16;
#pragma unroll
    for (int ct = 0; ct < NT; ++ct) {
        float b = bias[ct * 16 + m];
        acc[0][ct] = f32x4{b, b, b, b};
        acc[1][ct] = f32x4{b, b, b, b};
    }
#pragma unroll
    for (int s = 0; s < NK; ++s) {
#pragma unroll
        for (int ct = 0; ct < NT; ++ct) {
            half8 bh = wf[(size_t)(s * NT + ct) * 64 + lane];
            // one B-load feeds two independent acc chains (ILP + half the L2 traffic)
            acc[0][ct] = __builtin_amdgcn_mfma_f32_16x16x32_f16(af[0][s], bh, acc[0][ct], 0, 0, 0);
            acc[1][ct] = __builtin_amdgcn_mfma_f32_16x16x32_f16(af[1][s], bh, acc[1][ct], 0, 0, 0);
        }
    }
}

// A-fragments read straight from the f16 LDS tile: one ds_read_b128 per chunk, zero VALU.
template <int K>
__device__ __forceinline__ void load_a_lds(const _Float16* __restrict__ lw, int m, int q,
                                           half8 af[4]) {
    const _Float16* rp = lw + m * PITCH_H + q * 8;
#pragma unroll
    for (int s = 0; s < K / 32; ++s) af[s] = *(const half8*)(rp + s * 32);
}

template <int N>
__device__ __forceinline__ void store_d_lds(_Float16* __restrict__ lw, int m, int q,
                                            const f32x4* acc, bool relu) {
#pragma unroll
    for (int ct = 0; ct < N / 16; ++ct) {
#pragma unroll
        for (int r = 0; r < 4; ++r) {
            float v = acc[ct][r];
            if (relu) v = fmaxf(v, 0.0f);
            lw[(q * 4 + r) * PITCH_H + ct * 16 + m] = (_Float16)v;   // ds_write_b16
        }
    }
}

__global__ __launch_bounds__(256, 2) void mlp_phi_mfma(
    const float* __restrict__ u,
    const float* __restrict__ b0, const float* __restrict__ b1,
    const float* __restrict__ b2, const float* __restrict__ b3,
    const short* __restrict__ ws,
    const float* __restrict__ var1, const float* __restrict__ var2,
    const float* __restrict__ var3, const float* __restrict__ var4,
    const float* __restrict__ var5, const float* __restrict__ var6,
    float* __restrict__ out) {
    // 4 waves/block, each wave owns 32 rows (two 16-row m-tiles) end-to-end.
    // No __syncthreads anywhere. f16 tiles: 4 x 32 x 136 x 2B = 34816 B LDS.
    __shared__ __align__(16) _Float16 lds[4 * 32 * PITCH_H];
    const int t = threadIdx.x, lane = t & 63, wave = t >> 6;
    const int m = lane & 15, q = lane >> 4;
    _Float16* lw = lds + wave * 32 * PITCH_H;
    const size_t row0 = (size_t)blockIdx.x * 128 + wave * 32;

    const half8* wf0 = (const half8*)(ws);
    const half8* wf1 = (const half8*)(ws + 8192);
    const half8* wf2 = (const half8*)(ws + 24576);
    const half8* wf3 = (const half8*)(ws + 32768);

    half8 af[2][4];
    f32x4 acc[2][8];

    // ---- Layer 0 (64 -> 128): A straight from global u, cvt fp32->f16 ----
#pragma unroll
    for (int mt = 0; mt < 2; ++mt) {
        const float* up = u + (row0 + mt * 16 + m) * 64;
#pragma unroll
        for (int s = 0; s < 2; ++s) {
            float4 v0 = *(const float4*)(up + s * 32 + q * 8);
            float4 v1 = *(const float4*)(up + s * 32 + q * 8 + 4);
            half8 a;
            a[0] = (_Float16)v0.x; a[1] = (_Float16)v0.y;
            a[2] = (_Float16)v0.z; a[3] = (_Float16)v0.w;
            a[4] = (_Float16)v1.x; a[5] = (_Float16)v1.y;
            a[6] = (_Float16)v1.z; a[7] = (_Float16)v1.w;
            af[mt][s] = a;
        }
    }
    layer_frag2<64, 128>(wf0, b0, af, lane, m, acc);
#pragma unroll
    for (int mt = 0; mt < 2; ++mt) store_d_lds<128>(lw + mt * 16 * PITCH_H, m, q, acc[mt], true);

    // ---- Layer 1 (128 -> 128) ----
#pragma unroll
    for (int mt = 0; mt < 2; ++mt) load_a_lds<128>(lw + mt * 16 * PITCH_H, m, q, af[mt]);
    layer_frag2<128, 128>(wf1, b1, af, lane, m, acc);
#pragma unroll
    for (int mt = 0; mt < 2; ++mt) store_d_lds<128>(lw + mt * 16 * PITCH_H, m, q, acc[mt], true);

    // ---- Layer 2 (128 -> 64) ----
#pragma unroll
    for (int mt = 0; mt < 2; ++mt) load_a_lds<128>(lw + mt * 16 * PITCH_H, m, q, af[mt]);
    layer_frag2<128, 64>(wf2, b2, af, lane, m, acc);
#pragma unroll
    for (int mt = 0; mt < 2; ++mt) store_d_lds<64>(lw + mt * 16 * PITCH_H, m, q, acc[mt], true);

    // ---- Layer 3 (64 -> 32): net stays in registers ----
#pragma unroll
    for (int mt = 0; mt < 2; ++mt) load_a_lds<64>(lw + mt * 16 * PITCH_H, m, q, af[mt]);

    // Prefetch epilogue u values so their latency hides behind layer-3 MFMAs.
    float ue[2][8];
#pragma unroll
    for (int mt = 0; mt < 2; ++mt)
#pragma unroll
        for (int ot = 0; ot < 2; ++ot)
#pragma unroll
            for (int r = 0; r < 4; ++r)
                ue[mt][ot * 4 + r] = u[(row0 + mt * 16 + q * 4 + r) * 64 + ot * 16 + m];

    layer_frag2<64, 32>(wf3, b3, af, lane, m, acc);   // acc[mt][0..1] = net tiles

    // ---- Epilogue: lane holds net[row=mt*16+q*4+r][col=ot*16+m] ----
    // Domain note: u in [1e-4, 1-1e-4] => lt in [-9.22, -1e-4]; every quantity is
    // finite in fp32, so the reference's nan_to_num is a no-op here (checks dropped).
#pragma unroll
    for (int ot = 0; ot < 2; ++ot) {
        const int d = ot * 16 + m;
        const float v1 = var1[d], v2 = var2[d], v3 = var3[d],
                    v4 = var4[d], v6 = var6[d];
        const float v5h = 0.5f * var5[d];
        const float c3 = v3 - v4 - v5h;            // li coefficient, hoisted
#pragma unroll
        for (int mt = 0; mt < 2; ++mt) {
#pragma unroll
            for (int r = 0; r < 4; ++r) {
                const size_t row = row0 + mt * 16 + q * 4 + r;
                const float net = acc[mt][ot][r];
                const float ud = ue[mt][ot * 4 + r];

                const float omu = 1.0f - ud;
                const float lt = __log2f(omu) * LN2_F;     // log(1-u) < 0
                const float x = -lt;                        // in (1e-4, 9.3)

                // E1 via Abramowitz-Stegun 5.1.53 (x<1) / 5.1.54 (x>=1)
                const float e1s = -__log2f(x) * LN2_F
                    + (-0.57721566f + x * (0.99999193f + x * (-0.24991055f
                    + x * (0.05519968f + x * (-0.00976004f + x * 0.00107857f)))));
                const float num = 0.2677737343f + x * (8.6347608925f + x * (18.0590169730f
                    + x * (8.5733287401f + x)));
                const float den = 3.9584969228f + x * (21.0996530827f + x * (25.6329561486f
                    + x * (9.5733223454f + x)));
                const float e1l = __expf(-x) * num * __builtin_amdgcn_rcpf(x * den);
                const float li = -((x < 1.0f) ? e1s : e1l); // _li(1-u)

                const float rl = __builtin_amdgcn_rcpf(lt); // 1/log_term
                const float phi = fmaf(v4, omu, v2) * rl
                                + (v5h * omu * (lt + 1.0f)) * rl * rl
                                + c3 * li;

                const float ud2 = ud * ud;
                const float ud4 = ud2 * ud2;
                const float p01 = ud4 * fmaf(-4.0f, ud, 5.0f);   // 5u^4 - 4u^5
                const float corr1 = p01 * (v1 + phi);
                const float d1 = ud - 1.0f;
                const float corr2 = v6 * ud * d1 * d1;           // u^3 - 2u^2 + u

                const float nt = fmaxf(net + corr1 + corr2, 0.0f);
                const float base = fmaf(-0.5f, ud2, 0.5f);       // (1-u^2)/2
                // base^(-nt) = exp2(-nt * log2(base)); v_exp_f32 is native exp2
                out[row * 32 + d] = __builtin_amdgcn_exp2f(-nt * __log2f(base));
            }
        }
    }
}

extern "C" void kernel_launch(void* const* d_in, const int* in_sizes, int n_in,
                              void* d_out, int out_size, void* d_ws, size_t ws_size,
                              hipStream_t stream) {
    const float* u    = (const float*)d_in[0];
    const float* W0   = (const float*)d_in[1];
    const float* b0   = (const float*)d_in[2];
    const float* W1   = (const float*)d_in[3];
    const float* b1   = (const float*)d_in[4];
    const float* W2   = (const float*)d_in[5];
    const float* b2   = (const float*)d_in[6];
    const float* W3   = (const float*)d_in[7];
    const float* b3   = (const float*)d_in[8];
    const float* var1 = (const float*)d_in[9];
    const float* var2 = (const float*)d_in[10];
    const float* var3 = (const float*)d_in[11];
    const float* var4 = (const float*)d_in[12];
    const float* var5 = (const float*)d_in[13];
    const float* var6 = (const float*)d_in[14];
    float* out = (float*)d_out;
    short* ws = (short*)d_ws;   // needs 69,632 B

    // Convert weights to f16 fragment layout (same work every launch).
    prep_weights<<<dim3(17), dim3(256), 0, stream>>>(W0, W1, W2, W3, ws);

    const int B = in_sizes[0] / 64;        // 262144 rows
    const int blocks = B / 128;            // 128 rows per block (32 per wave)
    mlp_phi_mfma<<<dim3(blocks), dim3(256), 0, stream>>>(
        u, b0, b1, b2, b3, ws,
        var1, var2, var3, var4, var5, var6, out);
}